// Round 8
// baseline (69.520 us; speedup 1.0000x reference)
//
#include <hip/hip_runtime.h>

#define TWO_N 8192
#define HALF_N 4096
#define DIM 256
#define PANEL_BYTES 8192                     // 16 rows x 256 el x 2B

#define NSB 32                               // 8192 / 256 superblocks
#define SB_ROWS 256
#define CH_COLS 32
#define CHUNK_BYTES (CH_COLS * DIM * 2)      // 16 KB (2 panels)
#define NCHUNK (SB_ROWS / CH_COLS)           // 8

#define KAPPA 14.426950408889634f            // 10*log2(e)
#define SQRT_KAPPA 3.798282565f
#define LN2 0.6931471805599453f

typedef __attribute__((ext_vector_type(8))) short bf16x8;
typedef __attribute__((ext_vector_type(8))) unsigned short ushort8;
typedef __attribute__((ext_vector_type(4))) float f32x4;

__device__ __forceinline__ float bf2f(unsigned short u) {
  return __uint_as_float(((unsigned int)u) << 16);
}
__device__ __forceinline__ unsigned short f2bf(float f) {
  unsigned int u = __float_as_uint(f);
  return (unsigned short)((u + 0x7FFFu + ((u >> 16) & 1u)) >> 16);
}
__device__ __forceinline__ void async_copy16(void* lds_dst, const void* g_src) {
  __builtin_amdgcn_global_load_lds(
      (const __attribute__((address_space(1))) unsigned int*)g_src,
      (__attribute__((address_space(3))) unsigned int*)lds_dst, 16, 0, 0);
}

// rnB layout: panel p (16 rows), byte offset p*8192 + kk*1024 + (g*16 + r)*16
// holds row (p*16+r), k-elements kk*32 + g*8 .. +8, as bf16 scaled by
// SQRT_KAPPA. So any MFMA dot of two stored rows = KAPPA * cos-sim.

// K1: normalize 16 rows (one panel) per block; write fragment-major rnB
// scaled by SQRT_KAPPA. Also zero rowsum and out.
__global__ __launch_bounds__(256) void k_norm(const float* __restrict__ zi,
                                              const float* __restrict__ zj,
                                              unsigned short* __restrict__ rnB,
                                              float* __restrict__ rowsum,
                                              float* __restrict__ out) {
  int p = blockIdx.x;
  int wave = threadIdx.x >> 6, lane = threadIdx.x & 63;
  int rp = wave * 4 + (lane >> 4);           // row within panel
  int row = p * 16 + rp;
  int kslot = lane & 15;                     // 16 elems per thread
  int k0 = kslot * 16;
  if (threadIdx.x < 16) rowsum[p * 16 + threadIdx.x] = 0.0f;
  if (p == 0 && threadIdx.x == 0) out[0] = 0.0f;

  const float* src = (row < HALF_N) ? (zi + (size_t)row * DIM)
                                    : (zj + (size_t)(row - HALF_N) * DIM);
  float4 v[4];
  #pragma unroll
  for (int q = 0; q < 4; ++q)
    v[q] = *reinterpret_cast<const float4*>(src + k0 + q * 4);
  float ss = 0.0f;
  #pragma unroll
  for (int q = 0; q < 4; ++q)
    ss += v[q].x * v[q].x + v[q].y * v[q].y + v[q].z * v[q].z + v[q].w * v[q].w;
  #pragma unroll
  for (int m = 1; m <= 8; m <<= 1) ss += __shfl_xor(ss, m, 64);
  float r = rsqrtf(ss) * SQRT_KAPPA;

  ushort8 u0, u1;
  #pragma unroll
  for (int q = 0; q < 2; ++q) {
    u0[q * 4 + 0] = f2bf(v[q].x * r); u0[q * 4 + 1] = f2bf(v[q].y * r);
    u0[q * 4 + 2] = f2bf(v[q].z * r); u0[q * 4 + 3] = f2bf(v[q].w * r);
    u1[q * 4 + 0] = f2bf(v[q + 2].x * r); u1[q * 4 + 1] = f2bf(v[q + 2].y * r);
    u1[q * 4 + 2] = f2bf(v[q + 2].z * r); u1[q * 4 + 3] = f2bf(v[q + 2].w * r);
  }
  int kk = kslot >> 1;
  int g = (kslot & 1) * 2;
  char* pb = (char*)rnB + (size_t)p * PANEL_BYTES + kk * 1024;
  *reinterpret_cast<ushort8*>(pb + (g * 16 + rp) * 16) = u0;
  *reinterpret_cast<ushort8*>(pb + ((g + 1) * 16 + rp) * 16) = u1;
}

// K2: symmetric Gram rowsums, 256x256 tile pairs {p, q=p+d mod 32}, 8 waves.
// Row-exp-sums -> rowsum[p rows] (register se, shfl-reduced, atomics at end).
// Col-exp-sums -> LDS colacc[256] (DS atomics), flushed once -> rowsum[q rows].
// Diagonal tiles (d==0) do rows only. Traffic: 256 KB/block x 528 = 135 MB.
__global__ __launch_bounds__(512, 4) void k_sim(const unsigned short* __restrict__ rnB,
                                                float* __restrict__ rowsum) {
  __shared__ alignas(16) char lds[2][CHUNK_BYTES];
  __shared__ float colacc[SB_ROWS];
  int p = blockIdx.x;
  int d = blockIdx.y;
  if (d == 16 && p >= 16) return;            // dedupe the involutive offset
  int q = (p + d) & (NSB - 1);
  bool diag = (d == 0);

  int tid = threadIdx.x;
  int wave = tid >> 6, lane = tid & 63;
  int lrow = lane & 15, kgrp = lane >> 4;
  int r0 = p * SB_ROWS + wave * 32;
  const char* base = (const char*)rnB;

  if (tid < SB_ROWS) colacc[tid] = 0.0f;

  // A: 2 strips (32 rows) per wave, linear loads from fragment-major panels.
  bf16x8 a[2][8];
  #pragma unroll
  for (int s = 0; s < 2; ++s) {
    const char* pa = base + (size_t)(p * 16 + wave * 2 + s) * PANEL_BYTES + lane * 16;
    #pragma unroll
    for (int kk = 0; kk < 8; ++kk)
      a[s][kk] = *reinterpret_cast<const bf16x8*>(pa + kk * 1024);
  }

  float se[2][4];
  #pragma unroll
  for (int s = 0; s < 2; ++s)
    #pragma unroll
    for (int g = 0; g < 4; ++g) se[s][g] = 0.0f;

  const char* cbase = base + (size_t)(q * 16) * PANEL_BYTES;
  auto stage = [&](int buf, int ch) {
    const char* gp = cbase + (size_t)ch * CHUNK_BYTES + wave * 1024 + lane * 16;
    char* dst = &lds[buf][wave * 1024];
    async_copy16(dst, gp);
    async_copy16(dst + 8192, gp + 8192);
  };

  stage(0, 0);
  __syncthreads();

  for (int ch = 0; ch < NCHUNK; ++ch) {
    if (ch + 1 < NCHUNK) stage((ch + 1) & 1, ch + 1);
    const char* lb = lds[ch & 1] + lane * 16;
    #pragma unroll
    for (int h = 0; h < 2; ++h) {
      f32x4 acc0 = {-KAPPA, -KAPPA, -KAPPA, -KAPPA};
      f32x4 acc1 = {-KAPPA, -KAPPA, -KAPPA, -KAPPA};
      #pragma unroll
      for (int kk = 0; kk < 8; ++kk) {
        bf16x8 b = *reinterpret_cast<const bf16x8*>(lb + h * 8192 + kk * 1024);
        acc0 = __builtin_amdgcn_mfma_f32_16x16x32_bf16(a[0][kk], b, acc0, 0, 0, 0);
        acc1 = __builtin_amdgcn_mfma_f32_16x16x32_bf16(a[1][kk], b, acc1, 0, 0, 0);
      }
      float scc = 0.0f;
      #pragma unroll
      for (int g = 0; g < 4; ++g) {
        float e0 = __builtin_amdgcn_exp2f(acc0[g]);
        float e1 = __builtin_amdgcn_exp2f(acc1[g]);
        se[0][g] += e0;
        se[1][g] += e1;
        scc += e0 + e1;
      }
      if (!diag) {
        // per-wave column sums of this half-chunk -> block col accumulator
        scc += __shfl_xor(scc, 16, 64);
        scc += __shfl_xor(scc, 32, 64);
        if (lane < 16) atomicAdd(&colacc[ch * CH_COLS + h * 16 + lane], scc);
      }
    }
    __syncthreads();   // drains stage(ch+1)'s vmcnt + our lgkm + colacc visible
  }

  // row sums: reduce over 16 column-lanes, one atomic per row
  #pragma unroll
  for (int s = 0; s < 2; ++s) {
    #pragma unroll
    for (int g = 0; g < 4; ++g) {
      float v = se[s][g];
      #pragma unroll
      for (int m = 1; m <= 8; m <<= 1) v += __shfl_xor(v, m, 64);
      if (lrow == 0) atomicAdd(&rowsum[r0 + 16 * s + kgrp * 4 + g], v);
    }
  }

  // col sums flush: tile cols c -> rows q*256 + c
  if (!diag && tid < SB_ROWS)
    atomicAdd(&rowsum[q * SB_ROWS + tid], colacc[tid]);
}

// K3: per pair (i, j=i+N): subtract self term, lse - pos for both rows.
// Stored dots are KAPPA-scaled: pos = LN2*dp, self = exp2(sf - KAPPA).
__global__ __launch_bounds__(256) void k_rowred(const unsigned short* __restrict__ rnB,
                                               const float* __restrict__ rowsum,
                                               float* __restrict__ out) {
  __shared__ float ls[4];
  int wave = threadIdx.x >> 6, lane = threadIdx.x & 63;
  int q = lane & 31;
  float local = 0.0f;
  #pragma unroll
  for (int t = 0; t < 8; ++t) {
    int i = blockIdx.x * 32 + wave * 8 + t;              // pair 0..4095
    int row = (lane >> 5) ? i + HALF_N : i;
    int panel = row >> 4, r = row & 15;
    const char* addr = (const char*)rnB + (size_t)panel * PANEL_BYTES +
                       (q >> 2) * 1024 + ((q & 3) * 16 + r) * 16;
    ushort8 own = *reinterpret_cast<const ushort8*>(addr);
    int4 ow = *reinterpret_cast<int4*>(&own);
    int4 pw;
    pw.x = __shfl_xor(ow.x, 32, 64); pw.y = __shfl_xor(ow.y, 32, 64);
    pw.z = __shfl_xor(ow.z, 32, 64); pw.w = __shfl_xor(ow.w, 32, 64);
    ushort8 part = *reinterpret_cast<ushort8*>(&pw);
    float dp = 0.0f, sf = 0.0f;
    #pragma unroll
    for (int e = 0; e < 8; ++e) {
      float av = bf2f(own[e]), bv = bf2f(part[e]);
      dp += av * bv;
      sf += av * av;
    }
    #pragma unroll
    for (int m = 1; m <= 16; m <<= 1) {
      dp += __shfl_xor(dp, m, 64);
      sf += __shfl_xor(sf, m, 64);
    }
    if (q == 0) {                     // lanes 0 (row i) and 32 (row j)
      float self = __builtin_amdgcn_exp2f(sf - KAPPA);
      float rs = rowsum[row] - self;
      float lse = 10.0f + LN2 * __builtin_amdgcn_logf(rs);  // logf = log2
      local += lse - LN2 * dp;        // pos = 10*d = LN2 * (KAPPA*d)
    }
  }
  local += __shfl_xor(local, 32, 64);
  if (lane == 0) ls[wave] = local;
  __syncthreads();
  if (threadIdx.x == 0)
    atomicAdd(out, (ls[0] + ls[1] + ls[2] + ls[3]) * (1.0f / TWO_N));
}

extern "C" void kernel_launch(void* const* d_in, const int* in_sizes, int n_in,
                              void* d_out, int out_size, void* d_ws, size_t ws_size,
                              hipStream_t stream) {
  const float* zi = (const float*)d_in[0];
  const float* zj = (const float*)d_in[1];
  unsigned short* rnB = (unsigned short*)d_ws;                      // 4 MB
  float* rowsum = (float*)((char*)d_ws + (size_t)TWO_N * DIM * 2);  // 32 KB
  float* out = (float*)d_out;

  hipLaunchKernelGGL(k_norm, dim3(TWO_N / 16), dim3(256), 0, stream, zi, zj, rnB, rowsum, out);
  hipLaunchKernelGGL(k_sim, dim3(NSB, 17), dim3(512), 0, stream, rnB, rowsum);
  hipLaunchKernelGGL(k_rowred, dim3(HALF_N / 32), dim3(256), 0, stream, rnB, rowsum, out);
}

// Round 9
// 53.489 us; speedup vs baseline: 1.2997x; 1.2997x over previous
//
#include <hip/hip_runtime.h>

#define TWO_N 8192
#define HALF_N 4096
#define DIM 256
#define PANEL_BYTES 8192                     // 16 rows x 256 el x 2B

#define NBLK 64                              // 8192 / 128 row-blocks
#define ROWS_PER_BLOCK 128

#define KAPPA 14.426950408889634f            // 10*log2(e)
#define SQRT_KAPPA 3.798282565f
#define LN2 0.6931471805599453f

typedef __attribute__((ext_vector_type(8))) short bf16x8;
typedef __attribute__((ext_vector_type(8))) unsigned short ushort8;
typedef __attribute__((ext_vector_type(4))) float f32x4;

__device__ __forceinline__ float bf2f(unsigned short u) {
  return __uint_as_float(((unsigned int)u) << 16);
}
__device__ __forceinline__ unsigned short f2bf(float f) {
  unsigned int u = __float_as_uint(f);
  return (unsigned short)((u + 0x7FFFu + ((u >> 16) & 1u)) >> 16);
}

// rnB layout: panel p (16 rows), byte offset p*8192 + kk*1024 + (g*16 + r)*16
// holds row (p*16+r), k-elements kk*32 + g*8 .. +8, as bf16 scaled by
// SQRT_KAPPA. So any MFMA dot of two stored rows = KAPPA * cos-sim.

// K1: normalize 16 rows (one panel) per block; write fragment-major rnB
// scaled by SQRT_KAPPA. Also zero rowsum and out.
__global__ __launch_bounds__(256) void k_norm(const float* __restrict__ zi,
                                              const float* __restrict__ zj,
                                              unsigned short* __restrict__ rnB,
                                              float* __restrict__ rowsum,
                                              float* __restrict__ out) {
  int p = blockIdx.x;
  int wave = threadIdx.x >> 6, lane = threadIdx.x & 63;
  int rp = wave * 4 + (lane >> 4);           // row within panel
  int row = p * 16 + rp;
  int kslot = lane & 15;                     // 16 elems per thread
  int k0 = kslot * 16;
  if (threadIdx.x < 16) rowsum[p * 16 + threadIdx.x] = 0.0f;
  if (p == 0 && threadIdx.x == 0) out[0] = 0.0f;

  const float* src = (row < HALF_N) ? (zi + (size_t)row * DIM)
                                    : (zj + (size_t)(row - HALF_N) * DIM);
  float4 v[4];
  #pragma unroll
  for (int q = 0; q < 4; ++q)
    v[q] = *reinterpret_cast<const float4*>(src + k0 + q * 4);
  float ss = 0.0f;
  #pragma unroll
  for (int q = 0; q < 4; ++q)
    ss += v[q].x * v[q].x + v[q].y * v[q].y + v[q].z * v[q].z + v[q].w * v[q].w;
  #pragma unroll
  for (int m = 1; m <= 8; m <<= 1) ss += __shfl_xor(ss, m, 64);
  float r = rsqrtf(ss) * SQRT_KAPPA;

  ushort8 u0, u1;
  #pragma unroll
  for (int q = 0; q < 2; ++q) {
    u0[q * 4 + 0] = f2bf(v[q].x * r); u0[q * 4 + 1] = f2bf(v[q].y * r);
    u0[q * 4 + 2] = f2bf(v[q].z * r); u0[q * 4 + 3] = f2bf(v[q].w * r);
    u1[q * 4 + 0] = f2bf(v[q + 2].x * r); u1[q * 4 + 1] = f2bf(v[q + 2].y * r);
    u1[q * 4 + 2] = f2bf(v[q + 2].z * r); u1[q * 4 + 3] = f2bf(v[q + 2].w * r);
  }
  int kk = kslot >> 1;
  int g = (kslot & 1) * 2;
  char* pb = (char*)rnB + (size_t)p * PANEL_BYTES + kk * 1024;
  *reinterpret_cast<ushort8*>(pb + (g * 16 + rp) * 16) = u0;
  *reinterpret_cast<ushort8*>(pb + ((g + 1) * 16 + rp) * 16) = u1;
}

// K2: symmetric Gram rowsums, NO LDS, NO barriers. rn (4 MB) is L2-resident;
// each wave streams B panel-fragments straight into registers (1 KB coalesced
// loads), double-buffered with static names. Tile pair {bi, bj=bi+d mod 64},
// 128x128, 4 waves x 32 rows. Row-sums -> register, atomics at end.
// Col-sums (transposed tile) -> direct global atomics per 16-col panel.
__global__ __launch_bounds__(256) void k_sim(const unsigned short* __restrict__ rnB,
                                             float* __restrict__ rowsum) {
  int bi = blockIdx.x;
  int d = blockIdx.y;
  if (d == 32 && bi >= 32) return;           // dedupe the involutive offset
  int bj = (bi + d) & (NBLK - 1);
  bool diag = (d == 0);

  int wave = threadIdx.x >> 6, lane = threadIdx.x & 63;
  int lrow = lane & 15, kgrp = lane >> 4;
  int r0 = bi * ROWS_PER_BLOCK + wave * 32;
  const char* base = (const char*)rnB;

  // A: 2 strips (32 rows) per wave, linear loads from fragment-major panels.
  bf16x8 a[2][8];
  #pragma unroll
  for (int s = 0; s < 2; ++s) {
    const char* pa = base + (size_t)(bi * 8 + wave * 2 + s) * PANEL_BYTES + lane * 16;
    #pragma unroll
    for (int kk = 0; kk < 8; ++kk)
      a[s][kk] = *reinterpret_cast<const bf16x8*>(pa + kk * 1024);
  }

  float se[2][4];
  #pragma unroll
  for (int s = 0; s < 2; ++s)
    #pragma unroll
    for (int g = 0; g < 4; ++g) se[s][g] = 0.0f;

  const char* cb = base + (size_t)(bj * 8) * PANEL_BYTES + lane * 16;

  bf16x8 b0[8], b1[8];
  #pragma unroll
  for (int kk = 0; kk < 8; ++kk)
    b0[kk] = *reinterpret_cast<const bf16x8*>(cb + kk * 1024);

  // one 16-col panel: 16 MFMA + exp-epilogue + row/col accumulation
  auto compute = [&](bf16x8 (&b)[8], int cp) {
    f32x4 acc0 = {-KAPPA, -KAPPA, -KAPPA, -KAPPA};
    f32x4 acc1 = {-KAPPA, -KAPPA, -KAPPA, -KAPPA};
    #pragma unroll
    for (int kk = 0; kk < 8; ++kk) {
      acc0 = __builtin_amdgcn_mfma_f32_16x16x32_bf16(a[0][kk], b[kk], acc0, 0, 0, 0);
      acc1 = __builtin_amdgcn_mfma_f32_16x16x32_bf16(a[1][kk], b[kk], acc1, 0, 0, 0);
    }
    float scc = 0.0f;
    #pragma unroll
    for (int g = 0; g < 4; ++g) {
      float e0 = __builtin_amdgcn_exp2f(acc0[g]);
      float e1 = __builtin_amdgcn_exp2f(acc1[g]);
      se[0][g] += e0;
      se[1][g] += e1;
      scc += e0 + e1;
    }
    if (!diag) {
      // column sums of this tile -> rows of bj (transposed tile)
      scc += __shfl_xor(scc, 16, 64);
      scc += __shfl_xor(scc, 32, 64);
      if (lane < 16)
        atomicAdd(&rowsum[bj * ROWS_PER_BLOCK + cp * 16 + lane], scc);
    }
  };

  #pragma unroll
  for (int cp = 0; cp < 8; cp += 2) {
    if (cp + 1 < 8) {
      const char* pb = cb + (size_t)(cp + 1) * PANEL_BYTES;
      #pragma unroll
      for (int kk = 0; kk < 8; ++kk)
        b1[kk] = *reinterpret_cast<const bf16x8*>(pb + kk * 1024);
    }
    compute(b0, cp);
    if (cp + 2 < 8) {
      const char* pb = cb + (size_t)(cp + 2) * PANEL_BYTES;
      #pragma unroll
      for (int kk = 0; kk < 8; ++kk)
        b0[kk] = *reinterpret_cast<const bf16x8*>(pb + kk * 1024);
    }
    compute(b1, cp + 1);
  }

  // row sums: reduce over 16 column-lanes, one atomic per row
  #pragma unroll
  for (int s = 0; s < 2; ++s) {
    #pragma unroll
    for (int g = 0; g < 4; ++g) {
      float v = se[s][g];
      #pragma unroll
      for (int m = 1; m <= 8; m <<= 1) v += __shfl_xor(v, m, 64);
      if (lrow == 0) atomicAdd(&rowsum[r0 + 16 * s + kgrp * 4 + g], v);
    }
  }
}

// K3: per pair (i, j=i+N): subtract self term, lse - pos for both rows.
// Stored dots are KAPPA-scaled: pos = LN2*dp, self = exp2(sf - KAPPA).
__global__ __launch_bounds__(256) void k_rowred(const unsigned short* __restrict__ rnB,
                                               const float* __restrict__ rowsum,
                                               float* __restrict__ out) {
  __shared__ float ls[4];
  int wave = threadIdx.x >> 6, lane = threadIdx.x & 63;
  int q = lane & 31;
  float local = 0.0f;
  #pragma unroll
  for (int t = 0; t < 8; ++t) {
    int i = blockIdx.x * 32 + wave * 8 + t;              // pair 0..4095
    int row = (lane >> 5) ? i + HALF_N : i;
    int panel = row >> 4, r = row & 15;
    const char* addr = (const char*)rnB + (size_t)panel * PANEL_BYTES +
                       (q >> 2) * 1024 + ((q & 3) * 16 + r) * 16;
    ushort8 own = *reinterpret_cast<const ushort8*>(addr);
    int4 ow = *reinterpret_cast<int4*>(&own);
    int4 pw;
    pw.x = __shfl_xor(ow.x, 32, 64); pw.y = __shfl_xor(ow.y, 32, 64);
    pw.z = __shfl_xor(ow.z, 32, 64); pw.w = __shfl_xor(ow.w, 32, 64);
    ushort8 part = *reinterpret_cast<ushort8*>(&pw);
    float dp = 0.0f, sf = 0.0f;
    #pragma unroll
    for (int e = 0; e < 8; ++e) {
      float av = bf2f(own[e]), bv = bf2f(part[e]);
      dp += av * bv;
      sf += av * av;
    }
    #pragma unroll
    for (int m = 1; m <= 16; m <<= 1) {
      dp += __shfl_xor(dp, m, 64);
      sf += __shfl_xor(sf, m, 64);
    }
    if (q == 0) {                     // lanes 0 (row i) and 32 (row j)
      float self = __builtin_amdgcn_exp2f(sf - KAPPA);
      float rs = rowsum[row] - self;
      float lse = 10.0f + LN2 * __builtin_amdgcn_logf(rs);  // logf = log2
      local += lse - LN2 * dp;        // pos = 10*d = LN2 * (KAPPA*d)
    }
  }
  local += __shfl_xor(local, 32, 64);
  if (lane == 0) ls[wave] = local;
  __syncthreads();
  if (threadIdx.x == 0)
    atomicAdd(out, (ls[0] + ls[1] + ls[2] + ls[3]) * (1.0f / TWO_N));
}

extern "C" void kernel_launch(void* const* d_in, const int* in_sizes, int n_in,
                              void* d_out, int out_size, void* d_ws, size_t ws_size,
                              hipStream_t stream) {
  const float* zi = (const float*)d_in[0];
  const float* zj = (const float*)d_in[1];
  unsigned short* rnB = (unsigned short*)d_ws;                      // 4 MB
  float* rowsum = (float*)((char*)d_ws + (size_t)TWO_N * DIM * 2);  // 32 KB
  float* out = (float*)d_out;

  hipLaunchKernelGGL(k_norm, dim3(TWO_N / 16), dim3(256), 0, stream, zi, zj, rnB, rowsum, out);
  hipLaunchKernelGGL(k_sim, dim3(NBLK, 33), dim3(256), 0, stream, rnB, rowsum);
  hipLaunchKernelGGL(k_rowred, dim3(HALF_N / 32), dim3(256), 0, stream, rnB, rowsum, out);
}

// Round 10
// 42.456 us; speedup vs baseline: 1.6375x; 1.2599x over previous
//
#include <hip/hip_runtime.h>

#define TWO_N 8192
#define HALF_N 4096
#define DIM 256
#define PANEL_BYTES 8192                     // 16 rows x 256 el x 2B

#define NBLK 64                              // 8192 / 128 row-blocks
#define ROWS_PER_BLOCK 128
#define CH_COLS 32
#define CHUNK_BYTES (CH_COLS * DIM * 2)      // 16 KB (2 panels)

#define KAPPA 14.426950408889634f            // 10*log2(e)
#define SQRT_KAPPA 3.798282565f
#define LN2 0.6931471805599453f

typedef __attribute__((ext_vector_type(8))) short bf16x8;
typedef __attribute__((ext_vector_type(8))) unsigned short ushort8;
typedef __attribute__((ext_vector_type(4))) float f32x4;

__device__ __forceinline__ float bf2f(unsigned short u) {
  return __uint_as_float(((unsigned int)u) << 16);
}
__device__ __forceinline__ unsigned short f2bf(float f) {
  unsigned int u = __float_as_uint(f);
  return (unsigned short)((u + 0x7FFFu + ((u >> 16) & 1u)) >> 16);
}
__device__ __forceinline__ void async_copy16(void* lds_dst, const void* g_src) {
  __builtin_amdgcn_global_load_lds(
      (const __attribute__((address_space(1))) unsigned int*)g_src,
      (__attribute__((address_space(3))) unsigned int*)lds_dst, 16, 0, 0);
}

// rnB layout: panel p (16 rows), byte offset p*8192 + kk*1024 + (g*16 + r)*16
// holds row (p*16+r), k-elements kk*32 + g*8 .. +8, as bf16 scaled by
// SQRT_KAPPA. So any MFMA dot of two stored rows = KAPPA * cos-sim.

// K1: normalize 16 rows (one panel) per block; write fragment-major rnB
// scaled by SQRT_KAPPA. Also zero rowsum and out.
__global__ __launch_bounds__(256) void k_norm(const float* __restrict__ zi,
                                              const float* __restrict__ zj,
                                              unsigned short* __restrict__ rnB,
                                              float* __restrict__ rowsum,
                                              float* __restrict__ out) {
  int p = blockIdx.x;
  int wave = threadIdx.x >> 6, lane = threadIdx.x & 63;
  int rp = wave * 4 + (lane >> 4);           // row within panel
  int row = p * 16 + rp;
  int kslot = lane & 15;                     // 16 elems per thread
  int k0 = kslot * 16;
  if (threadIdx.x < 16) rowsum[p * 16 + threadIdx.x] = 0.0f;
  if (p == 0 && threadIdx.x == 0) out[0] = 0.0f;

  const float* src = (row < HALF_N) ? (zi + (size_t)row * DIM)
                                    : (zj + (size_t)(row - HALF_N) * DIM);
  float4 v[4];
  #pragma unroll
  for (int q = 0; q < 4; ++q)
    v[q] = *reinterpret_cast<const float4*>(src + k0 + q * 4);
  float ss = 0.0f;
  #pragma unroll
  for (int q = 0; q < 4; ++q)
    ss += v[q].x * v[q].x + v[q].y * v[q].y + v[q].z * v[q].z + v[q].w * v[q].w;
  #pragma unroll
  for (int m = 1; m <= 8; m <<= 1) ss += __shfl_xor(ss, m, 64);
  float r = rsqrtf(ss) * SQRT_KAPPA;

  ushort8 u0, u1;
  #pragma unroll
  for (int q = 0; q < 2; ++q) {
    u0[q * 4 + 0] = f2bf(v[q].x * r); u0[q * 4 + 1] = f2bf(v[q].y * r);
    u0[q * 4 + 2] = f2bf(v[q].z * r); u0[q * 4 + 3] = f2bf(v[q].w * r);
    u1[q * 4 + 0] = f2bf(v[q + 2].x * r); u1[q * 4 + 1] = f2bf(v[q + 2].y * r);
    u1[q * 4 + 2] = f2bf(v[q + 2].z * r); u1[q * 4 + 3] = f2bf(v[q + 2].w * r);
  }
  int kk = kslot >> 1;
  int g = (kslot & 1) * 2;
  char* pb = (char*)rnB + (size_t)p * PANEL_BYTES + kk * 1024;
  *reinterpret_cast<ushort8*>(pb + (g * 16 + rp) * 16) = u0;
  *reinterpret_cast<ushort8*>(pb + ((g + 1) * 16 + rp) * 16) = u1;
}

// K2: symmetric Gram rowsums, 128-row block x 512-col span, tri-buffered LDS
// with counted vmcnt(4) (one stage always in flight across each barrier).
// Pairs {bi, bj = bi+dd mod 64}: span s covers dd = 4s..4s+3 (s=0 includes
// the diagonal tile), s=8 is the single dd=32 tile, deduped by bi<32.
// Row-exp-sums -> registers -> atomics at end; col-exp-sums (transposed
// tiles) -> direct global atomics per 16-col panel.
__global__ __launch_bounds__(256, 3) void k_sim(const unsigned short* __restrict__ rnB,
                                                float* __restrict__ rowsum) {
  __shared__ alignas(16) char lds[3][CHUNK_BYTES];
  int bi = blockIdx.x;
  int s = blockIdx.y;
  if (s == 8 && bi >= 32) return;            // dedupe dd=32 involution
  const int NT = (s == 8) ? 4 : 16;          // chunks of 32 cols
  int dd0 = s * 4;

  int wave = threadIdx.x >> 6, lane = threadIdx.x & 63;
  int lrow = lane & 15, kgrp = lane >> 4;
  int r0 = bi * ROWS_PER_BLOCK + wave * 32;
  const char* base = (const char*)rnB;

  // A: 2 strips (32 rows) per wave, linear loads from fragment-major panels.
  bf16x8 a[2][8];
  #pragma unroll
  for (int st = 0; st < 2; ++st) {
    const char* pa = base + (size_t)(bi * 8 + wave * 2 + st) * PANEL_BYTES + lane * 16;
    #pragma unroll
    for (int kk = 0; kk < 8; ++kk)
      a[st][kk] = *reinterpret_cast<const bf16x8*>(pa + kk * 1024);
  }

  float se[2][4];
  #pragma unroll
  for (int st = 0; st < 2; ++st)
    #pragma unroll
    for (int g = 0; g < 4; ++g) se[st][g] = 0.0f;

  // stage chunk ch (32 cols of tile ch>>2) into lds[buf]; 4 KB per wave,
  // perfectly linear (LDS image == global fragment-major bytes).
  auto stage = [&](int buf, int ch) {
    int bj = (bi + dd0 + (ch >> 2)) & (NBLK - 1);
    const char* gp = base + ((size_t)bj * 8 + (size_t)(ch & 3) * 2) * PANEL_BYTES +
                     wave * 4096 + lane * 16;
    char* dst = &lds[buf][wave * 4096];
    #pragma unroll
    for (int q = 0; q < 4; ++q)
      async_copy16(dst + q * 1024, gp + q * 1024);
  };

  stage(0, 0);
  stage(1, 1);
  asm volatile("s_waitcnt vmcnt(4)" ::: "memory");   // chunk 0 landed
  __builtin_amdgcn_s_barrier();

  for (int ch = 0; ch < NT; ++ch) {
    if (ch + 2 < NT) stage((ch + 2) % 3, ch + 2);
    const char* lb = lds[ch % 3] + lane * 16;
    int bjc = (bi + dd0 + (ch >> 2)) & (NBLK - 1);
    bool diag = (dd0 + (ch >> 2)) == 0;
    #pragma unroll
    for (int h = 0; h < 2; ++h) {
      f32x4 acc0 = {-KAPPA, -KAPPA, -KAPPA, -KAPPA};
      f32x4 acc1 = {-KAPPA, -KAPPA, -KAPPA, -KAPPA};
      __builtin_amdgcn_s_setprio(1);
      #pragma unroll
      for (int kk = 0; kk < 8; ++kk) {
        bf16x8 b = *reinterpret_cast<const bf16x8*>(lb + h * 8192 + kk * 1024);
        acc0 = __builtin_amdgcn_mfma_f32_16x16x32_bf16(a[0][kk], b, acc0, 0, 0, 0);
        acc1 = __builtin_amdgcn_mfma_f32_16x16x32_bf16(a[1][kk], b, acc1, 0, 0, 0);
      }
      __builtin_amdgcn_s_setprio(0);
      float scc = 0.0f;
      #pragma unroll
      for (int g = 0; g < 4; ++g) {
        float e0 = __builtin_amdgcn_exp2f(acc0[g]);
        float e1 = __builtin_amdgcn_exp2f(acc1[g]);
        se[0][g] += e0;
        se[1][g] += e1;
        scc += e0 + e1;
      }
      if (!diag) {
        // column sums of this 16-col panel -> rows of bjc (transposed tile)
        scc += __shfl_xor(scc, 16, 64);
        scc += __shfl_xor(scc, 32, 64);
        if (lane < 16)
          atomicAdd(&rowsum[bjc * ROWS_PER_BLOCK + (ch & 3) * CH_COLS + h * 16 + lane], scc);
      }
    }
    if (ch + 1 < NT) {
      // counted drain: next chunk landed; keep the one after in flight.
      if (ch + 2 < NT)
        asm volatile("s_waitcnt vmcnt(4)" ::: "memory");
      else
        asm volatile("s_waitcnt vmcnt(0)" ::: "memory");
      __builtin_amdgcn_s_barrier();
    }
  }

  // row sums: reduce over 16 column-lanes, one atomic per row
  #pragma unroll
  for (int st = 0; st < 2; ++st) {
    #pragma unroll
    for (int g = 0; g < 4; ++g) {
      float v = se[st][g];
      #pragma unroll
      for (int m = 1; m <= 8; m <<= 1) v += __shfl_xor(v, m, 64);
      if (lrow == 0) atomicAdd(&rowsum[r0 + 16 * st + kgrp * 4 + g], v);
    }
  }
}

// K3: per pair (i, j=i+N): subtract self term, lse - pos for both rows.
// Stored dots are KAPPA-scaled: pos = LN2*dp, self = exp2(sf - KAPPA).
__global__ __launch_bounds__(256) void k_rowred(const unsigned short* __restrict__ rnB,
                                               const float* __restrict__ rowsum,
                                               float* __restrict__ out) {
  __shared__ float ls[4];
  int wave = threadIdx.x >> 6, lane = threadIdx.x & 63;
  int q = lane & 31;
  float local = 0.0f;
  #pragma unroll
  for (int t = 0; t < 8; ++t) {
    int i = blockIdx.x * 32 + wave * 8 + t;              // pair 0..4095
    int row = (lane >> 5) ? i + HALF_N : i;
    int panel = row >> 4, r = row & 15;
    const char* addr = (const char*)rnB + (size_t)panel * PANEL_BYTES +
                       (q >> 2) * 1024 + ((q & 3) * 16 + r) * 16;
    ushort8 own = *reinterpret_cast<const ushort8*>(addr);
    int4 ow = *reinterpret_cast<int4*>(&own);
    int4 pw;
    pw.x = __shfl_xor(ow.x, 32, 64); pw.y = __shfl_xor(ow.y, 32, 64);
    pw.z = __shfl_xor(ow.z, 32, 64); pw.w = __shfl_xor(ow.w, 32, 64);
    ushort8 part = *reinterpret_cast<ushort8*>(&pw);
    float dp = 0.0f, sf = 0.0f;
    #pragma unroll
    for (int e = 0; e < 8; ++e) {
      float av = bf2f(own[e]), bv = bf2f(part[e]);
      dp += av * bv;
      sf += av * av;
    }
    #pragma unroll
    for (int m = 1; m <= 16; m <<= 1) {
      dp += __shfl_xor(dp, m, 64);
      sf += __shfl_xor(sf, m, 64);
    }
    if (q == 0) {                     // lanes 0 (row i) and 32 (row j)
      float self = __builtin_amdgcn_exp2f(sf - KAPPA);
      float rs = rowsum[row] - self;
      float lse = 10.0f + LN2 * __builtin_amdgcn_logf(rs);  // logf = log2
      local += lse - LN2 * dp;        // pos = 10*d = LN2 * (KAPPA*d)
    }
  }
  local += __shfl_xor(local, 32, 64);
  if (lane == 0) ls[wave] = local;
  __syncthreads();
  if (threadIdx.x == 0)
    atomicAdd(out, (ls[0] + ls[1] + ls[2] + ls[3]) * (1.0f / TWO_N));
}

extern "C" void kernel_launch(void* const* d_in, const int* in_sizes, int n_in,
                              void* d_out, int out_size, void* d_ws, size_t ws_size,
                              hipStream_t stream) {
  const float* zi = (const float*)d_in[0];
  const float* zj = (const float*)d_in[1];
  unsigned short* rnB = (unsigned short*)d_ws;                      // 4 MB
  float* rowsum = (float*)((char*)d_ws + (size_t)TWO_N * DIM * 2);  // 32 KB
  float* out = (float*)d_out;

  hipLaunchKernelGGL(k_norm, dim3(TWO_N / 16), dim3(256), 0, stream, zi, zj, rnB, rowsum, out);
  hipLaunchKernelGGL(k_sim, dim3(NBLK, 9), dim3(256), 0, stream, rnB, rowsum);
  hipLaunchKernelGGL(k_rowred, dim3(HALF_N / 32), dim3(256), 0, stream, rnB, rowsum, out);
}